// Round 9
// baseline (327.927 us; speedup 1.0000x reference)
//
#include <hip/hip_runtime.h>
#include <math.h>

#define ROWS 8192
#define NCOL 2048
#define V 16
#define THREADS 256   // w0,w1 = pred row (logical lanes 0..127); w2,w3 = targ row

// static compare-exchange: ascending, both indices compile-time
__device__ __forceinline__ void ce(float& a, float& b) {
  const float lo = fminf(a, b);
  const float hi = fmaxf(a, b);
  a = lo; b = hi;
}

// med3(a,b,-inf)=min(a,b); med3(a,b,+inf)=max(a,b).
__device__ __forceinline__ float ce_dir(float a, float b, float cdir) {
  return __builtin_amdgcn_fmed3f(a, b, cdir);
}

template <int CTRL>
__device__ __forceinline__ float dpp_mov(float x) {
  return __builtin_bit_cast(
      float, __builtin_amdgcn_update_dpp(0, __builtin_bit_cast(int, x),
                                         CTRL, 0xF, 0xF, true));
}

template <int PAT>
__device__ __forceinline__ float swz(float x) {
  return __builtin_bit_cast(
      float, __builtin_amdgcn_ds_swizzle(__builtin_bit_cast(int, x), PAT));
}

// cross-lane partner fetch x[lane ^ M]: DPP (VALU pipe, per-SIMD) where an
// exact control exists; ds_swizzle / bpermute (DS pipe, per-CU) otherwise.
// DS is shared by 4 SIMDs, so only non-DPP-able masks stay on it.
template <int M>
__device__ __forceinline__ float lane_xor(float x, int a32, int a63) {
  if constexpr (M == 1)       return dpp_mov<0xB1>(x);    // quad_perm [1,0,3,2]
  else if constexpr (M == 2)  return dpp_mov<0x4E>(x);    // quad_perm [2,3,0,1]
  else if constexpr (M == 3)  return dpp_mov<0x1B>(x);    // quad_perm [3,2,1,0]
  else if constexpr (M == 7)  return dpp_mov<0x141>(x);   // row_half_mirror
  else if constexpr (M == 8)  return dpp_mov<0x128>(x);   // row_ror:8 == xor-8
  else if constexpr (M == 15) return dpp_mov<0x140>(x);   // row_mirror
  else if constexpr (M == 4)  return swz<0x101F>(x);      // BitMode xor-4
  else if constexpr (M == 16) return swz<0x401F>(x);      // BitMode xor-16
  else if constexpr (M == 31) return swz<0x7C1F>(x);      // BitMode xor-31
  else if constexpr (M == 32) {
    return __builtin_bit_cast(
        float, __builtin_amdgcn_ds_bpermute(a32, __builtin_bit_cast(int, x)));
  } else {                                                // M == 63
    return __builtin_bit_cast(
        float, __builtin_amdgcn_ds_bpermute(a63, __builtin_bit_cast(int, x)));
  }
}

// cross-lane xor pass, same element index, mask M (keep min iff (lane&M)==0).
template <int M>
__device__ __forceinline__ void xpass(float (&x)[V], float cdir,
                                      int a32, int a63) {
#pragma unroll
  for (int c = 0; c < V; c += 8) {
    float o[8];
#pragma unroll
    for (int u = 0; u < 8; ++u) o[u] = lane_xor<M>(x[c + u], a32, a63);
#pragma unroll
    for (int u = 0; u < 8; ++u) x[c + u] = ce_dir(x[c + u], o[u], cdir);
  }
}

// In-wave bitonic merge stage s = S (run length 16*2S -> merged):
// flip (partner lane^(2S-1), elem v^15), xor passes S/2..1, tail j=8..1.
template <int S>
__device__ __forceinline__ void mergeS(float (&x)[V], int lane,
                                       int a32, int a63) {
  {
    constexpr int LM = 2 * S - 1;
    const float cdir = (lane & S) ? INFINITY : -INFINITY;
#pragma unroll
    for (int q = 0; q < 2; ++q) {
      const int vA = 4 * q;
      float o[8];
#pragma unroll
      for (int u = 0; u < 4; ++u) {
        o[u]     = lane_xor<LM>(x[(vA + u) ^ 15], a32, a63);
        o[u + 4] = lane_xor<LM>(x[vA + u], a32, a63);
      }
#pragma unroll
      for (int u = 0; u < 4; ++u) {
        x[vA + u]        = ce_dir(x[vA + u],        o[u],     cdir);
        x[(vA + u) ^ 15] = ce_dir(x[(vA + u) ^ 15], o[u + 4], cdir);
      }
    }
  }
  if constexpr (S >= 32) xpass<16>(x, (lane & 16) ? INFINITY : -INFINITY, a32, a63);
  if constexpr (S >= 16) xpass<8>(x, (lane & 8) ? INFINITY : -INFINITY, a32, a63);
  if constexpr (S >= 8)  xpass<4>(x, (lane & 4) ? INFINITY : -INFINITY, a32, a63);
  if constexpr (S >= 4)  xpass<2>(x, (lane & 2) ? INFINITY : -INFINITY, a32, a63);
  if constexpr (S >= 2)  xpass<1>(x, (lane & 1) ? INFINITY : -INFINITY, a32, a63);
#pragma unroll
  for (int j = 8; j >= 1; j >>= 1) {
#pragma unroll
    for (int v = 0; v < V; ++v) {
      if ((v & j) == 0) ce(x[v], x[v | j]);
    }
  }
}

// TWO WAVES PER ROW, V=16 (round 9). Rounds 0-8 held >=32 live floats/lane;
// the allocator parks the overflow in AGPRs regardless of launch bounds
// (VGPR_Count 28-48 every round) and the accvgpr round-trips inflate VALU
// ~2.2x (R7: hand-count 2.3k vs measured ~5.1k instr/wave). With V=16 the
// live set (~34 regs) fits pure VGPRs even at 8 waves/SIMD. Lane-space is
// 128: stages s=1..32 stay in-wave; ONLY the s=64 flip (mask L^127) crosses
// waves, via one LDS exchange. MSE pairing via LDS publish (reused buffer).
__global__ __launch_bounds__(THREADS, 8) void sort_mse_kernel(
    const float* __restrict__ pred, const float* __restrict__ targ,
    float* __restrict__ out) {
  const int lane = threadIdx.x & 63;
  const int wave = threadIdx.x >> 6;
  const int wp = wave & 1;        // which half of the row's 128 logical lanes
  const int role = wave >> 1;     // 0 = pred (accumulate), 1 = targ (publish)
  const int row = blockIdx.x;
  const size_t base = (size_t)row * NCOL + (size_t)(wp * 64 + lane) * V;
  const int a32 = ((lane ^ 32) << 2);  // bpermute byte addrs, computed once
  const int a63 = ((lane ^ 63) << 2);
  // 16B-block swizzle: lane l's quad q stored at slot q ^ sw(l). Spreads the
  // 64-lane b128 ops (lane stride 64 B) across all 32 banks.
  const int swl = (lane ^ (lane >> 2)) & 3;

  __shared__ float lds[4][64][V];  // 16 KB: one 4 KB region per wave

  float x[V];
  const float4* s4 = (const float4*)((role ? targ : pred) + base);
#pragma unroll
  for (int q = 0; q < 4; ++q) {
    const float4 a = s4[q];
    x[4 * q + 0] = a.x; x[4 * q + 1] = a.y;
    x[4 * q + 2] = a.z; x[4 * q + 3] = a.w;
  }

  // ---- Phase 1: stages k = 2..16, fully in-lane, fully static ----
#pragma unroll
  for (int k = 2; k <= V; k <<= 1) {
#pragma unroll
    for (int v = 0; v < V; ++v) {
      if ((v & (k >> 1)) == 0) ce(x[v], x[v ^ (k - 1)]);
    }
#pragma unroll
    for (int j = k >> 2; j >= 1; j >>= 1) {
#pragma unroll
      for (int v = 0; v < V; ++v) {
        if ((v & j) == 0) ce(x[v], x[v | j]);
      }
    }
  }

  // ---- Phase 2: in-wave merge stages s = 1..32 ----
  mergeS<1>(x, lane, a32, a63);
  mergeS<2>(x, lane, a32, a63);
  mergeS<4>(x, lane, a32, a63);
  mergeS<8>(x, lane, a32, a63);
  mergeS<16>(x, lane, a32, a63);
  mergeS<32>(x, lane, a32, a63);

  // ---- Stage s = 64: flip partner = (other wave, lane^63, v^15) ----
#pragma unroll
  for (int q = 0; q < 4; ++q) {
    *(float4*)&lds[wave][lane][4 * (q ^ swl)] =
        make_float4(x[4 * q + 0], x[4 * q + 1], x[4 * q + 2], x[4 * q + 3]);
  }
  __syncthreads();
  {
    const int ls = lane ^ 63;
    const int swls = (ls ^ (ls >> 2)) & 3;
    const float cdir64 = wp ? INFINITY : -INFINITY;  // keep min iff (L&64)==0
    float4 t4[4];
#pragma unroll
    for (int q = 0; q < 4; ++q) {
      t4[q] = *(const float4*)&lds[wave ^ 1][ls][4 * ((3 - q) ^ swls)];
    }
    // o[4q+i] = partner x[(4q+i)^15] = t4[q][3-i]
#pragma unroll
    for (int q = 0; q < 4; ++q) {
      x[4 * q + 0] = ce_dir(x[4 * q + 0], t4[q].w, cdir64);
      x[4 * q + 1] = ce_dir(x[4 * q + 1], t4[q].z, cdir64);
      x[4 * q + 2] = ce_dir(x[4 * q + 2], t4[q].y, cdir64);
      x[4 * q + 3] = ce_dir(x[4 * q + 3], t4[q].x, cdir64);
    }
  }
  // remaining xor passes m = 32..1, then in-lane tail
  xpass<32>(x, (lane & 32) ? INFINITY : -INFINITY, a32, a63);
  xpass<16>(x, (lane & 16) ? INFINITY : -INFINITY, a32, a63);
  xpass<8>(x, (lane & 8) ? INFINITY : -INFINITY, a32, a63);
  xpass<4>(x, (lane & 4) ? INFINITY : -INFINITY, a32, a63);
  xpass<2>(x, (lane & 2) ? INFINITY : -INFINITY, a32, a63);
  xpass<1>(x, (lane & 1) ? INFINITY : -INFINITY, a32, a63);
#pragma unroll
  for (int j = 8; j >= 1; j >>= 1) {
#pragma unroll
    for (int v = 0; v < V; ++v) {
      if ((v & j) == 0) ce(x[v], x[v | j]);
    }
  }

  // ---- publish (targ) / accumulate (pred): same swizzled layout ----
  __syncthreads();  // all flip reads done before targ regions are overwritten
  if (role == 1) {
#pragma unroll
    for (int q = 0; q < 4; ++q) {
      *(float4*)&lds[wave][lane][4 * (q ^ swl)] =
          make_float4(x[4 * q + 0], x[4 * q + 1], x[4 * q + 2], x[4 * q + 3]);
    }
  }
  __syncthreads();
  if (role == 0) {
    float acc = 0.f;
#pragma unroll
    for (int q = 0; q < 4; ++q) {
      const float4 t = *(const float4*)&lds[wave + 2][lane][4 * (q ^ swl)];
      float d;
      d = x[4 * q + 0] - t.x; acc = fmaf(d, d, acc);
      d = x[4 * q + 1] - t.y; acc = fmaf(d, d, acc);
      d = x[4 * q + 2] - t.z; acc = fmaf(d, d, acc);
      d = x[4 * q + 3] - t.w; acc = fmaf(d, d, acc);
    }
#pragma unroll
    for (int off = 32; off > 0; off >>= 1) acc += __shfl_down(acc, off, 64);
    if (lane == 0) {
      unsafeAtomicAdd(out, acc * (1.0f / ((float)ROWS * (float)NCOL)));
    }
  }
}

extern "C" void kernel_launch(void* const* d_in, const int* in_sizes, int n_in,
                              void* d_out, int out_size, void* d_ws, size_t ws_size,
                              hipStream_t stream) {
  const float* pred = (const float*)d_in[0];
  const float* targ = (const float*)d_in[1];
  float* out = (float*)d_out;

  hipMemsetAsync(out, 0, sizeof(float), stream);  // d_out is re-poisoned 0xAA
  sort_mse_kernel<<<ROWS, THREADS, 0, stream>>>(pred, targ, out);
}

// Round 12
// 234.873 us; speedup vs baseline: 1.3962x; 1.3962x over previous
//
#include <hip/hip_runtime.h>
#include <math.h>

#define ROWS 8192
#define NCOL 2048
#define V 32
#define THREADS 256           // 4 waves: w0,w1 sort pred rows; w2,w3 sort targ

// static compare-exchange: ascending, both indices compile-time
__device__ __forceinline__ void ce(float& a, float& b) {
  const float lo = fminf(a, b);
  const float hi = fmaxf(a, b);
  a = lo; b = hi;
}

// med3(a,b,-inf)=min(a,b); med3(a,b,+inf)=max(a,b).
__device__ __forceinline__ float ce_dir(float a, float b, float cdir) {
  return __builtin_amdgcn_fmed3f(a, b, cdir);
}

// Pin every sort value into an ARCH VGPR (not AGPR) at this program point.
// Zero instructions emitted; the "+v" constraint forbids AGPR-parking.
// Evidence this parking exists: R8's DPP passes need ~46 arch VGPRs for
// x[32]+temps (DPP can't read AGPRs) yet VGPR_Count=28 -> compiler streams
// 8-wide batches through VGPR temps with v_accvgpr_read/write pairs = the
// persistent ~2x VALU inflation. Non-volatile: outputs feed the dataflow,
// so the asm can't be elided, and the scheduler keeps full freedom.
__device__ __forceinline__ void pin_vgpr(float (&x)[V]) {
#pragma unroll
  for (int v = 0; v < V; ++v) asm("" : "+v"(x[v]));
}

template <int CTRL>
__device__ __forceinline__ float dpp_mov(float x) {
  return __builtin_bit_cast(
      float, __builtin_amdgcn_update_dpp(0, __builtin_bit_cast(int, x),
                                         CTRL, 0xF, 0xF, true));
}

template <int PAT>
__device__ __forceinline__ float swz(float x) {
  return __builtin_bit_cast(
      float, __builtin_amdgcn_ds_swizzle(__builtin_bit_cast(int, x), PAT));
}

// cross-lane partner fetch x[lane ^ M]: DPP (VALU pipe) where an exact
// control exists; ds_swizzle / bpermute (DS pipe) otherwise.
template <int M>
__device__ __forceinline__ float lane_xor(float x, int a63) {
  if constexpr (M == 1)       return dpp_mov<0xB1>(x);    // quad_perm [1,0,3,2]
  else if constexpr (M == 2)  return dpp_mov<0x4E>(x);    // quad_perm [2,3,0,1]
  else if constexpr (M == 3)  return dpp_mov<0x1B>(x);    // quad_perm [3,2,1,0]
  else if constexpr (M == 7)  return dpp_mov<0x141>(x);   // row_half_mirror
  else if constexpr (M == 8)  return dpp_mov<0x128>(x);   // row_ror:8 == xor-8
  else if constexpr (M == 15) return dpp_mov<0x140>(x);   // row_mirror
  else if constexpr (M == 4)  return swz<0x101F>(x);      // BitMode xor-4
  else if constexpr (M == 16) return swz<0x401F>(x);      // BitMode xor-16
  else if constexpr (M == 31) return swz<0x7C1F>(x);      // BitMode xor-31
  else {                                                  // M == 63: bpermute
    return __builtin_bit_cast(
        float, __builtin_amdgcn_ds_bpermute(a63, __builtin_bit_cast(int, x)));
  }
}

// cross-lane xor pass over one array, same element index, mask M.
template <int M>
__device__ __forceinline__ void xpass1(float (&x)[V], float cdir, int a63) {
#pragma unroll
  for (int c = 0; c < V; c += 8) {
    float o[8];
#pragma unroll
    for (int u = 0; u < 8; ++u) o[u] = lane_xor<M>(x[c + u], a63);
#pragma unroll
    for (int u = 0; u < 8; ++u) x[c + u] = ce_dir(x[c + u], o[u], cdir);
  }
}

// One bitonic merge stage for run length k = 64*KB (KB = 1..32):
// flip pass (partner lane^(2KB-1), elem v^31), xor passes KB/2..1,
// then the in-lane tail j = 16..1.
template <int KB>
__device__ __forceinline__ void merge1(float (&x)[V], int lane, int a63) {
  {
    constexpr int LM = 2 * KB - 1;
    const float cdir = (lane & KB) ? INFINITY : -INFINITY;
#pragma unroll
    for (int q = 0; q < 4; ++q) {
      const int vA = 4 * q;
      float o[8];
#pragma unroll
      for (int u = 0; u < 4; ++u) {
        o[u]     = lane_xor<LM>(x[(vA + u) ^ 31], a63);
        o[u + 4] = lane_xor<LM>(x[vA + u], a63);
      }
#pragma unroll
      for (int u = 0; u < 4; ++u) {
        x[vA + u]        = ce_dir(x[vA + u],        o[u],     cdir);
        x[(vA + u) ^ 31] = ce_dir(x[(vA + u) ^ 31], o[u + 4], cdir);
      }
    }
  }
  if constexpr (KB >= 32) xpass1<16>(x, (lane & 16) ? INFINITY : -INFINITY, a63);
  if constexpr (KB >= 16) xpass1<8>(x, (lane & 8) ? INFINITY : -INFINITY, a63);
  if constexpr (KB >= 8)  xpass1<4>(x, (lane & 4) ? INFINITY : -INFINITY, a63);
  if constexpr (KB >= 4)  xpass1<2>(x, (lane & 2) ? INFINITY : -INFINITY, a63);
  if constexpr (KB >= 2)  xpass1<1>(x, (lane & 1) ? INFINITY : -INFINITY, a63);
  // in-lane xor passes j = 16..1: static indices AND static direction
#pragma unroll
  for (int j = 16; j >= 1; j >>= 1) {
#pragma unroll
    for (int v = 0; v < V; ++v) {
      if ((v & j) == 0) ce(x[v], x[v | j]);
    }
  }
  pin_vgpr(x);  // keep the whole array in arch VGPRs across stage boundaries
}

// Full normalized bitonic sort of one 2048-run (32 values/lane x 64 lanes).
__device__ __forceinline__ void sort_one(float (&x)[V], int lane, int a63) {
  // ---- Phase 1: stages k = 2..32, fully in-lane, fully static ----
#pragma unroll
  for (int k = 2; k <= V; k <<= 1) {
#pragma unroll
    for (int v = 0; v < V; ++v) {
      if ((v & (k >> 1)) == 0) ce(x[v], x[v ^ (k - 1)]);
    }
#pragma unroll
    for (int j = k >> 2; j >= 1; j >>= 1) {
#pragma unroll
      for (int v = 0; v < V; ++v) {
        if ((v & j) == 0) ce(x[v], x[v | j]);
      }
    }
  }
  pin_vgpr(x);
  // ---- Phase 2: stages k = 64..2048 ----
  merge1<1>(x, lane, a63);
  merge1<2>(x, lane, a63);
  merge1<4>(x, lane, a63);
  merge1<8>(x, lane, a63);
  merge1<16>(x, lane, a63);
  merge1<32>(x, lane, a63);
}

// Round-7/8 occupancy structure (best bench, 233.4 us): ONE array per wave.
// Waves 0-1 sort pred rows (keep in regs); waves 2-3 sort matching targ
// rows, publish via LDS. This round adds ONLY the pin_vgpr() calls.
__global__ __launch_bounds__(THREADS, 6) void sort_mse_kernel(
    const float* __restrict__ pred, const float* __restrict__ targ,
    float* __restrict__ out) {
  const int lane = threadIdx.x & 63;
  const int wave = threadIdx.x >> 6;
  const int pair = wave & 1;      // which of the block's 2 rows
  const int role = wave >> 1;     // 0 = pred (accumulate), 1 = targ (publish)
  const int row = blockIdx.x * 2 + pair;
  const size_t base = (size_t)row * NCOL + (size_t)lane * V;
  const int a63 = ((lane ^ 63) << 2);  // bpermute byte addr, computed once

  // 2 rows x 2048 floats = 16 KB; bank-swizzled access (see below)
  __shared__ float tbuf[2][NCOL];

  float x[V];
  const float4* s4 = (const float4*)((role ? targ : pred) + base);
#pragma unroll
  for (int q = 0; q < V / 4; ++q) {
    const float4 a = s4[q];
    x[4 * q + 0] = a.x; x[4 * q + 1] = a.y;
    x[4 * q + 2] = a.z; x[4 * q + 3] = a.w;
  }
  pin_vgpr(x);

  sort_one(x, lane, a63);

  // targ waves publish sorted rows. Physical placement: logical word
  // (lane,v=4q+i) -> word lane*32 + 4*(q^(lane&7)) + i; XOR on the 16B-block
  // index spreads each b128 op across all banks (2 lanes/bank = free).
  if (role == 1) {
#pragma unroll
    for (int q = 0; q < V / 4; ++q) {
      const int w = lane * V + 4 * (q ^ (lane & 7));
      *(float4*)&tbuf[pair][w] =
          make_float4(x[4 * q + 0], x[4 * q + 1], x[4 * q + 2], x[4 * q + 3]);
    }
  }
  __syncthreads();
  if (role == 1) return;

  // pred waves: read partner's sorted row back in the SAME swizzled layout.
  float acc = 0.f;
#pragma unroll
  for (int q = 0; q < V / 4; ++q) {
    const int w = lane * V + 4 * (q ^ (lane & 7));
    const float4 t4 = *(const float4*)&tbuf[pair][w];
    float d;
    d = x[4 * q + 0] - t4.x; acc = fmaf(d, d, acc);
    d = x[4 * q + 1] - t4.y; acc = fmaf(d, d, acc);
    d = x[4 * q + 2] - t4.z; acc = fmaf(d, d, acc);
    d = x[4 * q + 3] - t4.w; acc = fmaf(d, d, acc);
  }
#pragma unroll
  for (int off = 32; off > 0; off >>= 1) acc += __shfl_down(acc, off, 64);
  if (lane == 0) {
    unsafeAtomicAdd(out, acc * (1.0f / ((float)ROWS * (float)NCOL)));
  }
}

extern "C" void kernel_launch(void* const* d_in, const int* in_sizes, int n_in,
                              void* d_out, int out_size, void* d_ws, size_t ws_size,
                              hipStream_t stream) {
  const float* pred = (const float*)d_in[0];
  const float* targ = (const float*)d_in[1];
  float* out = (float*)d_out;

  hipMemsetAsync(out, 0, sizeof(float), stream);  // d_out is re-poisoned 0xAA
  sort_mse_kernel<<<ROWS / 2, THREADS, 0, stream>>>(pred, targ, out);
}